// Round 6
// baseline (309.941 us; speedup 1.0000x reference)
//
#include <hip/hip_runtime.h>

#define B_ 4
#define S_ 2048
#define D_ 1024
#define H_ 16
#define E_ 64
#define M_ (B_*S_)   // 8192

typedef __attribute__((ext_vector_type(8))) short short8;   // 8 bf16 = 4 VGPRs (MFMA A/B frag)
typedef __attribute__((ext_vector_type(4))) float floatx4;  // MFMA C/D frag

// async global->LDS, 16B per lane; dest must be linear (wave base + lane*16)
#define GLD16(g, l) __builtin_amdgcn_global_load_lds( \
    (const __attribute__((address_space(1))) unsigned*)(g), \
    (__attribute__((address_space(3))) unsigned*)(l), 16, 0, 0)

__device__ __forceinline__ ushort f2b(float f) {   // fp32 -> bf16 RNE
    union { float f; unsigned u; } v; v.f = f;
    unsigned r = v.u + 0x7fffu + ((v.u >> 16) & 1u);
    return (ushort)(r >> 16);
}
__device__ __forceinline__ float fast_exp2(float x) {
#if __has_builtin(__builtin_amdgcn_exp2f)
    return __builtin_amdgcn_exp2f(x);
#else
    float r; asm("v_exp_f32 %0, %1" : "=v"(r) : "v"(x)); return r;
#endif
}

// ---------------- plain cast fp32 -> bf16 (vector8) ----------------
__global__ __launch_bounds__(256) void cast_bf16(const float* __restrict__ in,
                                                 ushort* __restrict__ out, int n8) {
    int i = blockIdx.x * 256 + threadIdx.x;
    int stride = gridDim.x * 256;
    for (; i < n8; i += stride) {
        float4 a = ((const float4*)in)[2 * i];
        float4 b = ((const float4*)in)[2 * i + 1];
        short8 o;
        o[0] = (short)f2b(a.x); o[1] = (short)f2b(a.y);
        o[2] = (short)f2b(a.z); o[3] = (short)f2b(a.w);
        o[4] = (short)f2b(b.x); o[5] = (short)f2b(b.y);
        o[6] = (short)f2b(b.z); o[7] = (short)f2b(b.w);
        ((short8*)out)[i] = o;
    }
}

// ---------------- W cast+transpose: [48][D][E] fp32 -> [48][E][D] bf16 ----------------
__global__ __launch_bounds__(256) void transpose_w(const float* __restrict__ Wq,
                                                   const float* __restrict__ Wk,
                                                   const float* __restrict__ Wv,
                                                   ushort* __restrict__ wt) {
    int g = blockIdx.y;                 // 0..47 (w*16+h)
    int d0 = blockIdx.x * 64;
    const float* W = (g < 16 ? Wq : (g < 32 ? Wk : Wv)) + (size_t)(g & 15) * (D_ * E_);
    __shared__ __align__(16) ushort T[64 * 80];   // T[e][d-col], pitch 80
    int t = threadIdx.x;
    #pragma unroll
    for (int it = 0; it < 4; ++it) {               // 64 d-rows x 16 float4 cols
        int i = it * 256 + t;
        int r = i >> 4, c = i & 15;
        float4 x = *(const float4*)(W + (size_t)(d0 + r) * E_ + c * 4);
        T[(c * 4 + 0) * 80 + r] = f2b(x.x);
        T[(c * 4 + 1) * 80 + r] = f2b(x.y);
        T[(c * 4 + 2) * 80 + r] = f2b(x.z);
        T[(c * 4 + 3) * 80 + r] = f2b(x.w);
    }
    __syncthreads();
    #pragma unroll
    for (int it = 0; it < 2; ++it) {               // 64 e-rows x 8 chunks of 8
        int i = it * 256 + t;
        int e = i >> 3, c = i & 7;
        short8 x = *(const short8*)&T[e * 80 + c * 8];
        *(short8*)&wt[((size_t)g * E_ + e) * D_ + d0 + c * 8] = x;
    }
}

// ---------------- V transpose: [bh][S][E] -> [bh][E][S] (bf16) ----------------
__global__ __launch_bounds__(256) void transpose_v(const ushort* __restrict__ v,
                                                   ushort* __restrict__ vt) {
    int s0 = blockIdx.x * 64;
    int bh = blockIdx.y;
    __shared__ __align__(16) ushort T[64 * 80];   // T[e][s-col]
    int t = threadIdx.x;
    #pragma unroll
    for (int it = 0; it < 2; ++it) {
        int i = it * 256 + t;
        int r = i >> 3, c = i & 7;                 // s-row r, e-chunk c
        short8 x = *(const short8*)&v[((size_t)bh * S_ + s0 + r) * E_ + c * 8];
        #pragma unroll
        for (int j = 0; j < 8; ++j) T[(c * 8 + j) * 80 + r] = (ushort)x[j];
    }
    __syncthreads();
    #pragma unroll
    for (int it = 0; it < 2; ++it) {
        int i = it * 256 + t;
        int e = i >> 3, c = i & 7;
        short8 x = *(const short8*)&T[e * 80 + c * 8];
        *(short8*)&vt[((size_t)bh * E_ + e) * S_ + s0 + c * 8] = x;
    }
}

// ---------------- QKV GEMM: [8192 x 1024] x [1024 x 64] per (w,h), bf16 MFMA ----------------
__global__ __launch_bounds__(256) void gemm_qkv(const ushort* __restrict__ xb,
                                                const ushort* __restrict__ wt,
                                                ushort* __restrict__ qkv) {
    const int m0 = blockIdx.x * 256;
    const int wh = blockIdx.y;           // 0..47
    const ushort* Wg = wt + (size_t)wh * (E_ * D_);
    ushort* outw = qkv + (size_t)(wh >> 4) * ((size_t)B_ * H_ * S_ * E_);
    const int h = wh & 15;

    __shared__ __align__(16) ushort As[256 * 32];   // [256][32] swizzled
    __shared__ __align__(16) ushort Bs[64 * 32];    // [64][32]  swizzled

    const int t = threadIdx.x, l = t & 63, wid = t >> 6;
    floatx4 acc[4][4] = {};

    for (int k0 = 0; k0 < D_; k0 += 32) {
        __syncthreads();
        #pragma unroll
        for (int it = 0; it < 4; ++it) {            // A: 1024 chunks
            int i = it * 256 + t;
            int r = i >> 2, cs = i & 3;
            int c = cs ^ ((r >> 1) & 3);
            GLD16(xb + (size_t)(m0 + r) * D_ + k0 + c * 8, &As[i * 8]);
        }
        {                                            // B: 256 chunks
            int r = t >> 2, cs = t & 3;
            int c = cs ^ ((r >> 1) & 3);
            GLD16(Wg + (size_t)r * D_ + k0 + c * 8, &Bs[t * 8]);
        }
        __syncthreads();

        short8 af[4], bf[4];
        #pragma unroll
        for (int mf = 0; mf < 4; ++mf) {
            int row = wid * 64 + 16 * mf + (l & 15);
            int c = (l >> 4) ^ ((row >> 1) & 3);
            af[mf] = *(const short8*)&As[row * 32 + c * 8];
        }
        #pragma unroll
        for (int nf = 0; nf < 4; ++nf) {
            int row = 16 * nf + (l & 15);
            int c = (l >> 4) ^ ((row >> 1) & 3);
            bf[nf] = *(const short8*)&Bs[row * 32 + c * 8];
        }
        #pragma unroll
        for (int mf = 0; mf < 4; ++mf)
            #pragma unroll
            for (int nf = 0; nf < 4; ++nf)
                acc[mf][nf] = __builtin_amdgcn_mfma_f32_16x16x32_bf16(af[mf], bf[nf], acc[mf][nf], 0, 0, 0);
    }

    #pragma unroll
    for (int mf = 0; mf < 4; ++mf)
        #pragma unroll
        for (int nf = 0; nf < 4; ++nf)
            #pragma unroll
            for (int r = 0; r < 4; ++r) {
                int m = m0 + wid * 64 + 16 * mf + (l >> 4) * 4 + r;
                int b = m >> 11, s = m & (S_ - 1);
                int e = 16 * nf + (l & 15);
                outw[((size_t)((b << 4) + h) * S_ + s) * E_ + e] = f2b(acc[mf][nf][r]);
            }
}

// ---------------- Flash attention (causal), bf16 MFMA, 2-phase, 128-row supertiles ----------------
// grid: 512 1-D blocks. Block n: x = n>>6 (0..7), bh = n&63 (XCD = bh%8 -> per-XCD L2-resident K/V).
// Block handles 2 balanced q-supertiles {x, 15-x} of 128 rows -> 34 KV-iterations exactly.
// 4 waves x 32 q-rows (M_rep=2): K/V LDS fragment reads amortized over 2x the output rows.
__global__ __launch_bounds__(256) void flash(const ushort* __restrict__ qg,
                                             const ushort* __restrict__ kg,
                                             const ushort* __restrict__ vtg,
                                             ushort* __restrict__ attn) {
    const int n = blockIdx.x;
    const int x = n >> 6;          // 0..7
    const int bh = n & 63;
    const int b = bh >> 4, h = bh & 15;
    const ushort* qb = qg + (size_t)bh * (S_ * E_);
    const ushort* kb = kg + (size_t)bh * (S_ * E_);
    const ushort* vb = vtg + (size_t)bh * (E_ * S_);

    __shared__ __align__(16) ushort Qs[128 * 64];     // [q][e]   swizzled
    __shared__ __align__(16) ushort Ks[2][64 * 64];   // [t][e]   swizzled, double-buffered
    __shared__ __align__(16) ushort Vs[2][64 * 64];   // [e][j]   swizzled, double-buffered
    __shared__ __align__(16) ushort Ps[4][32 * 64];   // per-wave [q32][j64] swizzled

    const int t = threadIdx.x, l = t & 63, wid = t >> 6;
    const float SC = 0.18033688f;                  // (1/sqrt(E)) * log2(e)
    const int sups[2] = {x, 15 - x};

    #pragma unroll 1
    for (int si = 0; si < 2; ++si) {
        const int sup = sups[si];
        const int ntiles = 2 * sup + 2;

        // prologue: stage Q supertile (128 rows) + first K/V tile
        #pragma unroll
        for (int it = 0; it < 4; ++it) {
            int i = it * 256 + t;
            int r = i >> 3, cs = i & 7, c = cs ^ (r & 7);
            GLD16(qb + (size_t)(sup * 128 + r) * E_ + c * 8, &Qs[i * 8]);
        }
        #pragma unroll
        for (int it = 0; it < 2; ++it) {
            int i = it * 256 + t;
            int r = i >> 3, cs = i & 7, c = cs ^ (r & 7);
            GLD16(kb + (size_t)r * E_ + c * 8, &Ks[0][i * 8]);
            GLD16(vb + (size_t)r * S_ + c * 8, &Vs[0][i * 8]);
        }
        __syncthreads();

        short8 qf[2][2];
        #pragma unroll
        for (int m = 0; m < 2; ++m)
            #pragma unroll
            for (int ks = 0; ks < 2; ++ks) {
                int row = wid * 32 + m * 16 + (l & 15);
                int c = ((l >> 4) + 4 * ks) ^ (row & 7);
                qf[m][ks] = *(const short8*)&Qs[row * 64 + c * 8];
            }

        floatx4 o[2][4] = {};
        float mr[2][4], lr[2][4];
        #pragma unroll
        for (int m = 0; m < 2; ++m)
            #pragma unroll
            for (int r = 0; r < 4; ++r) { mr[m][r] = -__builtin_inff(); lr[m][r] = 0.f; }

        int buf = 0;
        for (int jt = 0; jt < ntiles; ++jt) {
            // issue next tile's staging BEFORE compute (latency hides under compute)
            if (jt + 1 < ntiles) {
                #pragma unroll
                for (int it = 0; it < 2; ++it) {
                    int i = it * 256 + t;
                    int r = i >> 3, cs = i & 7, c = cs ^ (r & 7);
                    GLD16(kb + (size_t)((jt + 1) * 64 + r) * E_ + c * 8, &Ks[buf ^ 1][i * 8]);
                    GLD16(vb + (size_t)r * S_ + (jt + 1) * 64 + c * 8, &Vs[buf ^ 1][i * 8]);
                }
            }

            // S = Q K^T (2 m-quadrants share each K fragment)
            floatx4 s[2][4] = {};
            #pragma unroll
            for (int nf = 0; nf < 4; ++nf) {
                #pragma unroll
                for (int ks = 0; ks < 2; ++ks) {
                    int row = 16 * nf + (l & 15);
                    int c = ((l >> 4) + 4 * ks) ^ (row & 7);
                    short8 kf = *(const short8*)&Ks[buf][row * 64 + c * 8];
                    s[0][nf] = __builtin_amdgcn_mfma_f32_16x16x32_bf16(qf[0][ks], kf, s[0][nf], 0, 0, 0);
                    s[1][nf] = __builtin_amdgcn_mfma_f32_16x16x32_bf16(qf[1][ks], kf, s[1][nf], 0, 0, 0);
                }
            }

            // scale (log2 domain) + causal mask (only last two tiles can mask)
            const bool maskt = (jt >= 2 * sup);
            #pragma unroll
            for (int m = 0; m < 2; ++m)
                #pragma unroll
                for (int nf = 0; nf < 4; ++nf) {
                    int colg = jt * 64 + 16 * nf + (l & 15);
                    int rowg = sup * 128 + wid * 32 + m * 16 + ((l >> 4) << 2);
                    #pragma unroll
                    for (int r = 0; r < 4; ++r) {
                        float v = s[m][nf][r] * SC;
                        if (maskt && colg > rowg + r) v = -__builtin_inff();
                        s[m][nf][r] = v;
                    }
                }

            // online softmax (rows live across 16-lane groups)
            #pragma unroll
            for (int m = 0; m < 2; ++m)
                #pragma unroll
                for (int r = 0; r < 4; ++r) {
                    float mx = fmaxf(fmaxf(s[m][0][r], s[m][1][r]), fmaxf(s[m][2][r], s[m][3][r]));
                    mx = fmaxf(mx, __shfl_xor(mx, 1));
                    mx = fmaxf(mx, __shfl_xor(mx, 2));
                    mx = fmaxf(mx, __shfl_xor(mx, 4));
                    mx = fmaxf(mx, __shfl_xor(mx, 8));
                    float mn = fmaxf(mr[m][r], mx);
                    float al = fast_exp2(mr[m][r] - mn);
                    mr[m][r] = mn;
                    float rs = 0.f;
                    #pragma unroll
                    for (int nf = 0; nf < 4; ++nf) {
                        float p = fast_exp2(s[m][nf][r] - mn);
                        s[m][nf][r] = p;
                        rs += p;
                    }
                    rs += __shfl_xor(rs, 1);
                    rs += __shfl_xor(rs, 2);
                    rs += __shfl_xor(rs, 4);
                    rs += __shfl_xor(rs, 8);
                    lr[m][r] = lr[m][r] * al + rs;
                    #pragma unroll
                    for (int nf = 0; nf < 4; ++nf) o[m][nf][r] *= al;
                }

            // P -> wave-private LDS (bf16, swizzled), rows 0..31
            #pragma unroll
            for (int m = 0; m < 2; ++m)
                #pragma unroll
                for (int nf = 0; nf < 4; ++nf)
                    #pragma unroll
                    for (int r = 0; r < 4; ++r) {
                        int row = m * 16 + (l >> 4) * 4 + r;
                        int col = 16 * nf + (l & 15);
                        int sw = (col >> 3) ^ (row & 7);
                        Ps[wid][row * 64 + sw * 8 + (col & 7)] = f2b(s[m][nf][r]);
                    }

            // O += P V (2 m-quadrants share each V fragment)
            short8 pf[2][2];
            #pragma unroll
            for (int m = 0; m < 2; ++m)
                #pragma unroll
                for (int ks = 0; ks < 2; ++ks) {
                    int row = m * 16 + (l & 15);
                    int c = ((l >> 4) + 4 * ks) ^ (row & 7);
                    pf[m][ks] = *(const short8*)&Ps[wid][row * 64 + c * 8];
                }
            #pragma unroll
            for (int nf = 0; nf < 4; ++nf) {
                #pragma unroll
                for (int ks = 0; ks < 2; ++ks) {
                    int row = 16 * nf + (l & 15);
                    int c = ((l >> 4) + 4 * ks) ^ (row & 7);
                    short8 vf = *(const short8*)&Vs[buf][row * 64 + c * 8];
                    o[0][nf] = __builtin_amdgcn_mfma_f32_16x16x32_bf16(pf[0][ks], vf, o[0][nf], 0, 0, 0);
                    o[1][nf] = __builtin_amdgcn_mfma_f32_16x16x32_bf16(pf[1][ks], vf, o[1][nf], 0, 0, 0);
                }
            }

            __syncthreads();   // drains this iteration's prefetch (vmcnt) + protects buf^1
            buf ^= 1;
        }

        // epilogue: normalize, bounce via Ps for coalesced bf16 writes
        #pragma unroll
        for (int m = 0; m < 2; ++m)
            #pragma unroll
            for (int r = 0; r < 4; ++r) {
                float inv = 1.0f / lr[m][r];
                #pragma unroll
                for (int nf = 0; nf < 4; ++nf) {
                    int row = m * 16 + (l >> 4) * 4 + r;
                    int col = 16 * nf + (l & 15);
                    int sw = (col >> 3) ^ (row & 7);
                    Ps[wid][row * 64 + sw * 8 + (col & 7)] = f2b(o[m][nf][r] * inv);
                }
            }
        #pragma unroll
        for (int it = 0; it < 4; ++it) {           // 32 rows x 8 chunks per wave
            int i = it * 64 + l;
            int row = i >> 3, cc = i & 7;
            int c = cc ^ (row & 7);
            short8 vv = *(const short8*)&Ps[wid][row * 64 + c * 8];
            int s_abs = sup * 128 + wid * 32 + row;
            *(short8*)&attn[((size_t)(b * S_ + s_abs)) * D_ + h * E_ + cc * 8] = vv;
        }
        __syncthreads();   // Ps/Qs reuse boundary before next supertile's staging
    }
}

// ---------------- output projection: [8192x1024] x Wp^T + bp, bf16 MFMA, fp32 out ----------------
__global__ __launch_bounds__(256) void out_proj(const ushort* __restrict__ a,
                                                const ushort* __restrict__ wpb,
                                                const float* __restrict__ bp,
                                                float* __restrict__ out) {
    const int m0 = blockIdx.x * 128;
    const int n0 = blockIdx.y * 128;

    __shared__ __align__(16) ushort As[128 * 32];
    __shared__ __align__(16) ushort Bs[128 * 32];

    const int t = threadIdx.x, l = t & 63, wid = t >> 6;
    const int wm = (wid & 1) * 64, wn = (wid >> 1) * 64;
    floatx4 acc[4][4] = {};

    for (int k0 = 0; k0 < D_; k0 += 32) {
        __syncthreads();
        #pragma unroll
        for (int it = 0; it < 2; ++it) {
            int i = it * 256 + t;
            int r = i >> 2, cs = i & 3;
            int c = cs ^ ((r >> 1) & 3);
            GLD16(a + (size_t)(m0 + r) * D_ + k0 + c * 8, &As[i * 8]);
            GLD16(wpb + (size_t)(n0 + r) * D_ + k0 + c * 8, &Bs[i * 8]);
        }
        __syncthreads();

        short8 af[4], bf[4];
        #pragma unroll
        for (int mf = 0; mf < 4; ++mf) {
            int row = wm + 16 * mf + (l & 15);
            int c = (l >> 4) ^ ((row >> 1) & 3);
            af[mf] = *(const short8*)&As[row * 32 + c * 8];
        }
        #pragma unroll
        for (int nf = 0; nf < 4; ++nf) {
            int row = wn + 16 * nf + (l & 15);
            int c = (l >> 4) ^ ((row >> 1) & 3);
            bf[nf] = *(const short8*)&Bs[row * 32 + c * 8];
        }
        #pragma unroll
        for (int mf = 0; mf < 4; ++mf)
            #pragma unroll
            for (int nf = 0; nf < 4; ++nf)
                acc[mf][nf] = __builtin_amdgcn_mfma_f32_16x16x32_bf16(af[mf], bf[nf], acc[mf][nf], 0, 0, 0);
    }

    #pragma unroll
    for (int nf = 0; nf < 4; ++nf) {
        int col = n0 + wn + 16 * nf + (l & 15);
        float bias = bp[col];
        #pragma unroll
        for (int mf = 0; mf < 4; ++mf)
            #pragma unroll
            for (int r = 0; r < 4; ++r) {
                int m = m0 + wm + 16 * mf + (l >> 4) * 4 + r;
                out[(size_t)m * D_ + col] = acc[mf][nf][r] + bias;
            }
    }
}

extern "C" void kernel_launch(void* const* d_in, const int* in_sizes, int n_in,
                              void* d_out, int out_size, void* d_ws, size_t ws_size,
                              hipStream_t stream) {
    const float* x  = (const float*)d_in[0];
    const float* Wq = (const float*)d_in[1];
    const float* Wk = (const float*)d_in[2];
    const float* Wv = (const float*)d_in[3];
    const float* Wp = (const float*)d_in[4];
    const float* bp = (const float*)d_in[5];

    ushort* ws = (ushort*)d_ws;
    const size_t NX  = (size_t)M_ * D_;          // 8M
    const size_t NW  = (size_t)48 * E_ * D_;     // 3.15M
    const size_t NP  = (size_t)D_ * D_;          // 1M
    const size_t QSZ = (size_t)B_ * H_ * S_ * E_;// 8M
    ushort* xb    = ws;
    ushort* wt    = xb + NX;
    ushort* wpb   = wt + NW;
    ushort* qkvb  = wpb + NP;        // q | k | v
    ushort* vt    = qkvb + 3 * QSZ;
    ushort* attnb = vt + QSZ;        // total ~104 MB

    cast_bf16  <<<2048, 256, 0, stream>>>(x, xb, (int)(NX / 8));
    cast_bf16  <<<512, 256, 0, stream>>>(Wp, wpb, (int)(NP / 8));
    transpose_w<<<dim3(16, 48), 256, 0, stream>>>(Wq, Wk, Wv, wt);
    gemm_qkv   <<<dim3(M_ / 256, 48), 256, 0, stream>>>(xb, wt, qkvb);
    transpose_v<<<dim3(S_ / 64, B_ * H_), 256, 0, stream>>>(qkvb + 2 * QSZ, vt);
    flash      <<<512, 256, 0, stream>>>(qkvb, qkvb + QSZ, vt, attnb);
    out_proj   <<<dim3(M_ / 128, D_ / 128), 256, 0, stream>>>(attnb, wpb, bp, (float*)d_out);
}

// Round 7
// 244.322 us; speedup vs baseline: 1.2686x; 1.2686x over previous
//
#include <hip/hip_runtime.h>

#define B_ 4
#define S_ 2048
#define D_ 1024
#define H_ 16
#define E_ 64
#define M_ (B_*S_)   // 8192

typedef __attribute__((ext_vector_type(8))) short short8;   // 8 bf16 = 4 VGPRs (MFMA A/B frag)
typedef __attribute__((ext_vector_type(4))) float floatx4;  // MFMA C/D frag

// async global->LDS, 16B per lane; dest must be linear (wave base + lane*16)
#define GLD16(g, l) __builtin_amdgcn_global_load_lds( \
    (const __attribute__((address_space(1))) unsigned*)(g), \
    (__attribute__((address_space(3))) unsigned*)(l), 16, 0, 0)

__device__ __forceinline__ ushort f2b(float f) {   // fp32 -> bf16 RNE
    union { float f; unsigned u; } v; v.f = f;
    unsigned r = v.u + 0x7fffu + ((v.u >> 16) & 1u);
    return (ushort)(r >> 16);
}
__device__ __forceinline__ float fast_exp2(float x) {
#if __has_builtin(__builtin_amdgcn_exp2f)
    return __builtin_amdgcn_exp2f(x);
#else
    float r; asm("v_exp_f32 %0, %1" : "=v"(r) : "v"(x)); return r;
#endif
}

// ---------------- plain cast fp32 -> bf16 (vector8) ----------------
__global__ __launch_bounds__(256) void cast_bf16(const float* __restrict__ in,
                                                 ushort* __restrict__ out, int n8) {
    int i = blockIdx.x * 256 + threadIdx.x;
    int stride = gridDim.x * 256;
    for (; i < n8; i += stride) {
        float4 a = ((const float4*)in)[2 * i];
        float4 b = ((const float4*)in)[2 * i + 1];
        short8 o;
        o[0] = (short)f2b(a.x); o[1] = (short)f2b(a.y);
        o[2] = (short)f2b(a.z); o[3] = (short)f2b(a.w);
        o[4] = (short)f2b(b.x); o[5] = (short)f2b(b.y);
        o[6] = (short)f2b(b.z); o[7] = (short)f2b(b.w);
        ((short8*)out)[i] = o;
    }
}

// ---------------- W cast+transpose: [48][D][E] fp32 -> [48][E][D] bf16 ----------------
__global__ __launch_bounds__(256) void transpose_w(const float* __restrict__ Wq,
                                                   const float* __restrict__ Wk,
                                                   const float* __restrict__ Wv,
                                                   ushort* __restrict__ wt) {
    int g = blockIdx.y;                 // 0..47 (w*16+h)
    int d0 = blockIdx.x * 64;
    const float* W = (g < 16 ? Wq : (g < 32 ? Wk : Wv)) + (size_t)(g & 15) * (D_ * E_);
    __shared__ __align__(16) ushort T[64 * 80];   // T[e][d-col], pitch 80
    int t = threadIdx.x;
    #pragma unroll
    for (int it = 0; it < 4; ++it) {               // 64 d-rows x 16 float4 cols
        int i = it * 256 + t;
        int r = i >> 4, c = i & 15;
        float4 x = *(const float4*)(W + (size_t)(d0 + r) * E_ + c * 4);
        T[(c * 4 + 0) * 80 + r] = f2b(x.x);
        T[(c * 4 + 1) * 80 + r] = f2b(x.y);
        T[(c * 4 + 2) * 80 + r] = f2b(x.z);
        T[(c * 4 + 3) * 80 + r] = f2b(x.w);
    }
    __syncthreads();
    #pragma unroll
    for (int it = 0; it < 2; ++it) {               // 64 e-rows x 8 chunks of 8
        int i = it * 256 + t;
        int e = i >> 3, c = i & 7;
        short8 x = *(const short8*)&T[e * 80 + c * 8];
        *(short8*)&wt[((size_t)g * E_ + e) * D_ + d0 + c * 8] = x;
    }
}

// ---------------- V transpose: [bh][S][E] -> [bh][E][S] (bf16) ----------------
__global__ __launch_bounds__(256) void transpose_v(const ushort* __restrict__ v,
                                                   ushort* __restrict__ vt) {
    int s0 = blockIdx.x * 64;
    int bh = blockIdx.y;
    __shared__ __align__(16) ushort T[64 * 80];   // T[e][s-col]
    int t = threadIdx.x;
    #pragma unroll
    for (int it = 0; it < 2; ++it) {
        int i = it * 256 + t;
        int r = i >> 3, c = i & 7;                 // s-row r, e-chunk c
        short8 x = *(const short8*)&v[((size_t)bh * S_ + s0 + r) * E_ + c * 8];
        #pragma unroll
        for (int j = 0; j < 8; ++j) T[(c * 8 + j) * 80 + r] = (ushort)x[j];
    }
    __syncthreads();
    #pragma unroll
    for (int it = 0; it < 2; ++it) {
        int i = it * 256 + t;
        int e = i >> 3, c = i & 7;
        short8 x = *(const short8*)&T[e * 80 + c * 8];
        *(short8*)&vt[((size_t)bh * E_ + e) * S_ + s0 + c * 8] = x;
    }
}

// ---------------- QKV GEMM: [8192 x 1024] x [1024 x 64] per (w,h), bf16 MFMA ----------------
__global__ __launch_bounds__(256) void gemm_qkv(const ushort* __restrict__ xb,
                                                const ushort* __restrict__ wt,
                                                ushort* __restrict__ qkv) {
    const int m0 = blockIdx.x * 256;
    const int wh = blockIdx.y;           // 0..47
    const ushort* Wg = wt + (size_t)wh * (E_ * D_);
    ushort* outw = qkv + (size_t)(wh >> 4) * ((size_t)B_ * H_ * S_ * E_);
    const int h = wh & 15;

    __shared__ __align__(16) ushort As[256 * 32];   // [256][32] swizzled
    __shared__ __align__(16) ushort Bs[64 * 32];    // [64][32]  swizzled

    const int t = threadIdx.x, l = t & 63, wid = t >> 6;
    floatx4 acc[4][4] = {};

    for (int k0 = 0; k0 < D_; k0 += 32) {
        __syncthreads();
        #pragma unroll
        for (int it = 0; it < 4; ++it) {            // A: 1024 chunks
            int i = it * 256 + t;
            int r = i >> 2, cs = i & 3;
            int c = cs ^ ((r >> 1) & 3);
            GLD16(xb + (size_t)(m0 + r) * D_ + k0 + c * 8, &As[i * 8]);
        }
        {                                            // B: 256 chunks
            int r = t >> 2, cs = t & 3;
            int c = cs ^ ((r >> 1) & 3);
            GLD16(Wg + (size_t)r * D_ + k0 + c * 8, &Bs[t * 8]);
        }
        __syncthreads();

        short8 af[4], bf[4];
        #pragma unroll
        for (int mf = 0; mf < 4; ++mf) {
            int row = wid * 64 + 16 * mf + (l & 15);
            int c = (l >> 4) ^ ((row >> 1) & 3);
            af[mf] = *(const short8*)&As[row * 32 + c * 8];
        }
        #pragma unroll
        for (int nf = 0; nf < 4; ++nf) {
            int row = 16 * nf + (l & 15);
            int c = (l >> 4) ^ ((row >> 1) & 3);
            bf[nf] = *(const short8*)&Bs[row * 32 + c * 8];
        }
        #pragma unroll
        for (int mf = 0; mf < 4; ++mf)
            #pragma unroll
            for (int nf = 0; nf < 4; ++nf)
                acc[mf][nf] = __builtin_amdgcn_mfma_f32_16x16x32_bf16(af[mf], bf[nf], acc[mf][nf], 0, 0, 0);
    }

    #pragma unroll
    for (int mf = 0; mf < 4; ++mf)
        #pragma unroll
        for (int nf = 0; nf < 4; ++nf)
            #pragma unroll
            for (int r = 0; r < 4; ++r) {
                int m = m0 + wid * 64 + 16 * mf + (l >> 4) * 4 + r;
                int b = m >> 11, s = m & (S_ - 1);
                int e = 16 * nf + (l & 15);
                outw[((size_t)((b << 4) + h) * S_ + s) * E_ + e] = f2b(acc[mf][nf][r]);
            }
}

// ---------------- Flash attention (causal), bf16 MFMA, 2-phase pipelined ----------------
// grid: 1024 1-D blocks. Block n: x = n>>6 (0..15), bh = n&63 (XCD = bh%8 -> per-XCD L2-resident K/V).
// Each block does 2 balanced q-tiles {x, 31-x} = exactly 33 KV-tiles.
// 48 KB LDS + 84 VGPR -> 3 blocks/CU resident (vs 2 before): more waves to hide the
// serialized QK->softmax->PV chain. Inner loop identical to the round-5 (153 us) code.
__global__ __launch_bounds__(256) void flash(const ushort* __restrict__ qg,
                                             const ushort* __restrict__ kg,
                                             const ushort* __restrict__ vtg,
                                             ushort* __restrict__ attn) {
    const int n = blockIdx.x;
    const int x = n >> 6;          // 0..15
    const int bh = n & 63;
    const int b = bh >> 4, h = bh & 15;
    const ushort* qb = qg + (size_t)bh * (S_ * E_);
    const ushort* kb = kg + (size_t)bh * (S_ * E_);
    const ushort* vb = vtg + (size_t)bh * (E_ * S_);

    __shared__ __align__(16) ushort Qs[64 * 64];      // [q][e]   swizzled
    __shared__ __align__(16) ushort Ks[2][64 * 64];   // [t][e]   swizzled, double-buffered
    __shared__ __align__(16) ushort Vs[2][64 * 64];   // [e][j]   swizzled, double-buffered
    __shared__ __align__(16) ushort Ps[4][16 * 64];   // per-wave [q16][j64] swizzled

    const int t = threadIdx.x, l = t & 63, wid = t >> 6;
    const float SC = 0.18033688f;                  // (1/sqrt(E)) * log2(e)
    const int ri_base = wid * 16 + ((l >> 4) << 2);
    const int qts[2] = {x, 31 - x};

    #pragma unroll 1
    for (int qi = 0; qi < 2; ++qi) {
        const int qt = qts[qi];

        // prologue: stage Q + first K/V tile
        #pragma unroll
        for (int it = 0; it < 2; ++it) {
            int i = it * 256 + t;
            int r = i >> 3, cs = i & 7, c = cs ^ (r & 7);
            GLD16(qb + (size_t)(qt * 64 + r) * E_ + c * 8, &Qs[i * 8]);
            GLD16(kb + (size_t)r * E_ + c * 8, &Ks[0][i * 8]);
            GLD16(vb + (size_t)r * S_ + c * 8, &Vs[0][i * 8]);
        }
        __syncthreads();

        short8 qf[2];
        #pragma unroll
        for (int ks = 0; ks < 2; ++ks) {
            int row = wid * 16 + (l & 15);
            int c = ((l >> 4) + 4 * ks) ^ (row & 7);
            qf[ks] = *(const short8*)&Qs[row * 64 + c * 8];
        }

        floatx4 o[4] = {};
        float mr[4], lr[4];
        #pragma unroll
        for (int r = 0; r < 4; ++r) { mr[r] = -__builtin_inff(); lr[r] = 0.f; }

        int buf = 0;
        for (int jt = 0; jt <= qt; ++jt) {
            // issue next tile's staging BEFORE compute (latency hides under compute)
            if (jt < qt) {
                #pragma unroll
                for (int it = 0; it < 2; ++it) {
                    int i = it * 256 + t;
                    int r = i >> 3, cs = i & 7, c = cs ^ (r & 7);
                    GLD16(kb + (size_t)((jt + 1) * 64 + r) * E_ + c * 8, &Ks[buf ^ 1][i * 8]);
                    GLD16(vb + (size_t)r * S_ + (jt + 1) * 64 + c * 8, &Vs[buf ^ 1][i * 8]);
                }
            }

            // S = Q K^T on current buffer
            floatx4 s[4] = {};
            #pragma unroll
            for (int nf = 0; nf < 4; ++nf) {
                #pragma unroll
                for (int ks = 0; ks < 2; ++ks) {
                    int row = 16 * nf + (l & 15);
                    int c = ((l >> 4) + 4 * ks) ^ (row & 7);
                    short8 kf = *(const short8*)&Ks[buf][row * 64 + c * 8];
                    s[nf] = __builtin_amdgcn_mfma_f32_16x16x32_bf16(qf[ks], kf, s[nf], 0, 0, 0);
                }
            }

            // scale (log2 domain) + causal mask on diagonal tile
            const bool diag = (jt == qt);
            #pragma unroll
            for (int nf = 0; nf < 4; ++nf) {
                int cj = 16 * nf + (l & 15);
                #pragma unroll
                for (int r = 0; r < 4; ++r) {
                    float v = s[nf][r] * SC;
                    if (diag && cj > ri_base + r) v = -__builtin_inff();
                    s[nf][r] = v;
                }
            }

            // online softmax (rows live across 16-lane groups)
            float al[4];
            #pragma unroll
            for (int r = 0; r < 4; ++r) {
                float mx = fmaxf(fmaxf(s[0][r], s[1][r]), fmaxf(s[2][r], s[3][r]));
                mx = fmaxf(mx, __shfl_xor(mx, 1));
                mx = fmaxf(mx, __shfl_xor(mx, 2));
                mx = fmaxf(mx, __shfl_xor(mx, 4));
                mx = fmaxf(mx, __shfl_xor(mx, 8));
                float mn = fmaxf(mr[r], mx);
                al[r] = fast_exp2(mr[r] - mn);
                mr[r] = mn;
                float rs = 0.f;
                #pragma unroll
                for (int nf = 0; nf < 4; ++nf) {
                    float p = fast_exp2(s[nf][r] - mn);
                    s[nf][r] = p;
                    rs += p;
                }
                rs += __shfl_xor(rs, 1);
                rs += __shfl_xor(rs, 2);
                rs += __shfl_xor(rs, 4);
                rs += __shfl_xor(rs, 8);
                lr[r] = lr[r] * al[r] + rs;
                #pragma unroll
                for (int nf = 0; nf < 4; ++nf) o[nf][r] *= al[r];
            }

            // P -> wave-private LDS (bf16, swizzled)
            #pragma unroll
            for (int nf = 0; nf < 4; ++nf)
                #pragma unroll
                for (int r = 0; r < 4; ++r) {
                    int row = (l >> 4) * 4 + r;
                    int col = 16 * nf + (l & 15);
                    int sw = (col >> 3) ^ (row & 7);
                    Ps[wid][row * 64 + sw * 8 + (col & 7)] = f2b(s[nf][r]);
                }

            // O += P V
            short8 pf[2];
            #pragma unroll
            for (int ks = 0; ks < 2; ++ks) {
                int row = l & 15;
                int c = ((l >> 4) + 4 * ks) ^ (row & 7);
                pf[ks] = *(const short8*)&Ps[wid][row * 64 + c * 8];
            }
            #pragma unroll
            for (int nf = 0; nf < 4; ++nf) {
                #pragma unroll
                for (int ks = 0; ks < 2; ++ks) {
                    int row = 16 * nf + (l & 15);
                    int c = ((l >> 4) + 4 * ks) ^ (row & 7);
                    short8 vf = *(const short8*)&Vs[buf][row * 64 + c * 8];
                    o[nf] = __builtin_amdgcn_mfma_f32_16x16x32_bf16(pf[ks], vf, o[nf], 0, 0, 0);
                }
            }

            __syncthreads();   // drains this iteration's prefetch (vmcnt) + protects buf^1
            buf ^= 1;
        }

        // epilogue: normalize, bounce via Ps for coalesced bf16 writes
        #pragma unroll
        for (int r = 0; r < 4; ++r) {
            float inv = 1.0f / lr[r];
            #pragma unroll
            for (int nf = 0; nf < 4; ++nf) {
                int row = (l >> 4) * 4 + r;
                int col = 16 * nf + (l & 15);
                int sw = (col >> 3) ^ (row & 7);
                Ps[wid][row * 64 + sw * 8 + (col & 7)] = f2b(o[nf][r] * inv);
            }
        }
        #pragma unroll
        for (int it = 0; it < 2; ++it) {               // 16 rows x 8 chunks per wave
            int i = it * 64 + l;
            int row = i >> 3, cc = i & 7;
            int c = cc ^ (row & 7);
            short8 vv = *(const short8*)&Ps[wid][row * 64 + c * 8];
            int s_abs = qt * 64 + wid * 16 + row;
            *(short8*)&attn[((size_t)(b * S_ + s_abs)) * D_ + h * E_ + cc * 8] = vv;
        }
        __syncthreads();   // Ps/Qs reuse boundary before next q-tile's staging
    }
}

// ---------------- output projection: [8192x1024] x Wp^T + bp, bf16 MFMA, fp32 out ----------------
__global__ __launch_bounds__(256) void out_proj(const ushort* __restrict__ a,
                                                const ushort* __restrict__ wpb,
                                                const float* __restrict__ bp,
                                                float* __restrict__ out) {
    const int m0 = blockIdx.x * 128;
    const int n0 = blockIdx.y * 128;

    __shared__ __align__(16) ushort As[128 * 32];
    __shared__ __align__(16) ushort Bs[128 * 32];

    const int t = threadIdx.x, l = t & 63, wid = t >> 6;
    const int wm = (wid & 1) * 64, wn = (wid >> 1) * 64;
    floatx4 acc[4][4] = {};

    for (int k0 = 0; k0 < D_; k0 += 32) {
        __syncthreads();
        #pragma unroll
        for (int it = 0; it < 2; ++it) {
            int i = it * 256 + t;
            int r = i >> 2, cs = i & 3;
            int c = cs ^ ((r >> 1) & 3);
            GLD16(a + (size_t)(m0 + r) * D_ + k0 + c * 8, &As[i * 8]);
            GLD16(wpb + (size_t)(n0 + r) * D_ + k0 + c * 8, &Bs[i * 8]);
        }
        __syncthreads();

        short8 af[4], bf[4];
        #pragma unroll
        for (int mf = 0; mf < 4; ++mf) {
            int row = wm + 16 * mf + (l & 15);
            int c = (l >> 4) ^ ((row >> 1) & 3);
            af[mf] = *(const short8*)&As[row * 32 + c * 8];
        }
        #pragma unroll
        for (int nf = 0; nf < 4; ++nf) {
            int row = wn + 16 * nf + (l & 15);
            int c = (l >> 4) ^ ((row >> 1) & 3);
            bf[nf] = *(const short8*)&Bs[row * 32 + c * 8];
        }
        #pragma unroll
        for (int mf = 0; mf < 4; ++mf)
            #pragma unroll
            for (int nf = 0; nf < 4; ++nf)
                acc[mf][nf] = __builtin_amdgcn_mfma_f32_16x16x32_bf16(af[mf], bf[nf], acc[mf][nf], 0, 0, 0);
    }

    #pragma unroll
    for (int nf = 0; nf < 4; ++nf) {
        int col = n0 + wn + 16 * nf + (l & 15);
        float bias = bp[col];
        #pragma unroll
        for (int mf = 0; mf < 4; ++mf)
            #pragma unroll
            for (int r = 0; r < 4; ++r) {
                int m = m0 + wm + 16 * mf + (l >> 4) * 4 + r;
                out[(size_t)m * D_ + col] = acc[mf][nf][r] + bias;
            }
    }
}

extern "C" void kernel_launch(void* const* d_in, const int* in_sizes, int n_in,
                              void* d_out, int out_size, void* d_ws, size_t ws_size,
                              hipStream_t stream) {
    const float* x  = (const float*)d_in[0];
    const float* Wq = (const float*)d_in[1];
    const float* Wk = (const float*)d_in[2];
    const float* Wv = (const float*)d_in[3];
    const float* Wp = (const float*)d_in[4];
    const float* bp = (const float*)d_in[5];

    ushort* ws = (ushort*)d_ws;
    const size_t NX  = (size_t)M_ * D_;          // 8M
    const size_t NW  = (size_t)48 * E_ * D_;     // 3.15M
    const size_t NP  = (size_t)D_ * D_;          // 1M
    const size_t QSZ = (size_t)B_ * H_ * S_ * E_;// 8M
    ushort* xb    = ws;
    ushort* wt    = xb + NX;
    ushort* wpb   = wt + NW;
    ushort* qkvb  = wpb + NP;        // q | k | v
    ushort* vt    = qkvb + 3 * QSZ;
    ushort* attnb = vt + QSZ;        // total ~104 MB

    cast_bf16  <<<2048, 256, 0, stream>>>(x, xb, (int)(NX / 8));
    cast_bf16  <<<512, 256, 0, stream>>>(Wp, wpb, (int)(NP / 8));
    transpose_w<<<dim3(16, 48), 256, 0, stream>>>(Wq, Wk, Wv, wt);
    gemm_qkv   <<<dim3(M_ / 256, 48), 256, 0, stream>>>(xb, wt, qkvb);
    transpose_v<<<dim3(S_ / 64, B_ * H_), 256, 0, stream>>>(qkvb + 2 * QSZ, vt);
    flash      <<<1024, 256, 0, stream>>>(qkvb, qkvb + QSZ, vt, attnb);
    out_proj   <<<dim3(M_ / 128, D_ / 128), 256, 0, stream>>>(attnb, wpb, bp, (float*)d_out);
}

// Round 9
// 223.992 us; speedup vs baseline: 1.3837x; 1.0908x over previous
//
#include <hip/hip_runtime.h>

#define B_ 4
#define S_ 2048
#define D_ 1024
#define H_ 16
#define E_ 64
#define M_ (B_*S_)   // 8192

typedef __attribute__((ext_vector_type(8))) short short8;   // 8 bf16 = 4 VGPRs (MFMA A/B frag)
typedef __attribute__((ext_vector_type(4))) float floatx4;  // MFMA C/D frag

// async global->LDS, 16B per lane; dest must be linear (wave base + lane*16)
#define GLD16(g, l) __builtin_amdgcn_global_load_lds( \
    (const __attribute__((address_space(1))) unsigned*)(g), \
    (__attribute__((address_space(3))) unsigned*)(l), 16, 0, 0)

__device__ __forceinline__ ushort f2b(float f) {   // fp32 -> bf16 RNE
    union { float f; unsigned u; } v; v.f = f;
    unsigned r = v.u + 0x7fffu + ((v.u >> 16) & 1u);
    return (ushort)(r >> 16);
}
__device__ __forceinline__ unsigned cvt_pk_bf16(float lo, float hi) {  // 2xf32 -> packed bf16x2
    unsigned r;
    asm("v_cvt_pk_bf16_f32 %0, %1, %2" : "=v"(r) : "v"(lo), "v"(hi));
    return r;
}
__device__ __forceinline__ float fast_exp2(float x) {
#if __has_builtin(__builtin_amdgcn_exp2f)
    return __builtin_amdgcn_exp2f(x);
#else
    float r; asm("v_exp_f32 %0, %1" : "=v"(r) : "v"(x)); return r;
#endif
}

// 12 balanced q-tile groups per bh: each sums to exactly 44 KV-tile-units.
__constant__ int GCNT[12] = {2,2,2,2,2,2,2,2,2,2,4,8};
__constant__ int GQT[12][8] = {
    {31,11, 0, 0, 0, 0, 0, 0}, {30,12, 0, 0, 0, 0, 0, 0},
    {29,13, 0, 0, 0, 0, 0, 0}, {28,14, 0, 0, 0, 0, 0, 0},
    {27,15, 0, 0, 0, 0, 0, 0}, {26,16, 0, 0, 0, 0, 0, 0},
    {25,17, 0, 0, 0, 0, 0, 0}, {24,18, 0, 0, 0, 0, 0, 0},
    {23,19, 0, 0, 0, 0, 0, 0}, {22,20, 0, 0, 0, 0, 0, 0},
    {21,10, 9, 0, 0, 0, 0, 0}, { 8, 7, 6, 5, 4, 3, 2, 1}
};

// ---------------- plain cast fp32 -> bf16 (vector8) ----------------
__global__ __launch_bounds__(256) void cast_bf16(const float* __restrict__ in,
                                                 ushort* __restrict__ out, int n8) {
    int i = blockIdx.x * 256 + threadIdx.x;
    int stride = gridDim.x * 256;
    for (; i < n8; i += stride) {
        float4 a = ((const float4*)in)[2 * i];
        float4 b = ((const float4*)in)[2 * i + 1];
        short8 o;
        o[0] = (short)f2b(a.x); o[1] = (short)f2b(a.y);
        o[2] = (short)f2b(a.z); o[3] = (short)f2b(a.w);
        o[4] = (short)f2b(b.x); o[5] = (short)f2b(b.y);
        o[6] = (short)f2b(b.z); o[7] = (short)f2b(b.w);
        ((short8*)out)[i] = o;
    }
}

// ---------------- W cast+transpose: [48][D][E] fp32 -> [48][E][D] bf16 ----------------
__global__ __launch_bounds__(256) void transpose_w(const float* __restrict__ Wq,
                                                   const float* __restrict__ Wk,
                                                   const float* __restrict__ Wv,
                                                   ushort* __restrict__ wt) {
    int g = blockIdx.y;                 // 0..47 (w*16+h)
    int d0 = blockIdx.x * 64;
    const float* W = (g < 16 ? Wq : (g < 32 ? Wk : Wv)) + (size_t)(g & 15) * (D_ * E_);
    __shared__ __align__(16) ushort T[64 * 80];   // T[e][d-col], pitch 80
    int t = threadIdx.x;
    #pragma unroll
    for (int it = 0; it < 4; ++it) {               // 64 d-rows x 16 float4 cols
        int i = it * 256 + t;
        int r = i >> 4, c = i & 15;
        float4 x = *(const float4*)(W + (size_t)(d0 + r) * E_ + c * 4);
        T[(c * 4 + 0) * 80 + r] = f2b(x.x);
        T[(c * 4 + 1) * 80 + r] = f2b(x.y);
        T[(c * 4 + 2) * 80 + r] = f2b(x.z);
        T[(c * 4 + 3) * 80 + r] = f2b(x.w);
    }
    __syncthreads();
    #pragma unroll
    for (int it = 0; it < 2; ++it) {               // 64 e-rows x 8 chunks of 8
        int i = it * 256 + t;
        int e = i >> 3, c = i & 7;
        short8 x = *(const short8*)&T[e * 80 + c * 8];
        *(short8*)&wt[((size_t)g * E_ + e) * D_ + d0 + c * 8] = x;
    }
}

// ---------------- V transpose: [bh][S][E] -> [bh][E][S] (bf16) ----------------
__global__ __launch_bounds__(256) void transpose_v(const ushort* __restrict__ v,
                                                   ushort* __restrict__ vt) {
    int s0 = blockIdx.x * 64;
    int bh = blockIdx.y;
    __shared__ __align__(16) ushort T[64 * 80];   // T[e][s-col]
    int t = threadIdx.x;
    #pragma unroll
    for (int it = 0; it < 2; ++it) {
        int i = it * 256 + t;
        int r = i >> 3, c = i & 7;                 // s-row r, e-chunk c
        short8 x = *(const short8*)&v[((size_t)bh * S_ + s0 + r) * E_ + c * 8];
        #pragma unroll
        for (int j = 0; j < 8; ++j) T[(c * 8 + j) * 80 + r] = (ushort)x[j];
    }
    __syncthreads();
    #pragma unroll
    for (int it = 0; it < 2; ++it) {
        int i = it * 256 + t;
        int e = i >> 3, c = i & 7;
        short8 x = *(const short8*)&T[e * 80 + c * 8];
        *(short8*)&vt[((size_t)bh * E_ + e) * S_ + s0 + c * 8] = x;
    }
}

// ---------------- QKV GEMM: [8192 x 1024] x [1024 x 64] per (w,h), bf16 MFMA ----------------
__global__ __launch_bounds__(256) void gemm_qkv(const ushort* __restrict__ xb,
                                                const ushort* __restrict__ wt,
                                                ushort* __restrict__ qkv) {
    const int m0 = blockIdx.x * 256;
    const int wh = blockIdx.y;           // 0..47
    const ushort* Wg = wt + (size_t)wh * (E_ * D_);
    ushort* outw = qkv + (size_t)(wh >> 4) * ((size_t)B_ * H_ * S_ * E_);
    const int h = wh & 15;

    __shared__ __align__(16) ushort As[256 * 32];   // [256][32] swizzled
    __shared__ __align__(16) ushort Bs[64 * 32];    // [64][32]  swizzled

    const int t = threadIdx.x, l = t & 63, wid = t >> 6;
    floatx4 acc[4][4] = {};

    for (int k0 = 0; k0 < D_; k0 += 32) {
        __syncthreads();
        #pragma unroll
        for (int it = 0; it < 4; ++it) {            // A: 1024 chunks
            int i = it * 256 + t;
            int r = i >> 2, cs = i & 3;
            int c = cs ^ ((r >> 1) & 3);
            GLD16(xb + (size_t)(m0 + r) * D_ + k0 + c * 8, &As[i * 8]);
        }
        {                                            // B: 256 chunks
            int r = t >> 2, cs = t & 3;
            int c = cs ^ ((r >> 1) & 3);
            GLD16(Wg + (size_t)r * D_ + k0 + c * 8, &Bs[t * 8]);
        }
        __syncthreads();

        short8 af[4], bf[4];
        #pragma unroll
        for (int mf = 0; mf < 4; ++mf) {
            int row = wid * 64 + 16 * mf + (l & 15);
            int c = (l >> 4) ^ ((row >> 1) & 3);
            af[mf] = *(const short8*)&As[row * 32 + c * 8];
        }
        #pragma unroll
        for (int nf = 0; nf < 4; ++nf) {
            int row = 16 * nf + (l & 15);
            int c = (l >> 4) ^ ((row >> 1) & 3);
            bf[nf] = *(const short8*)&Bs[row * 32 + c * 8];
        }
        #pragma unroll
        for (int mf = 0; mf < 4; ++mf)
            #pragma unroll
            for (int nf = 0; nf < 4; ++nf)
                acc[mf][nf] = __builtin_amdgcn_mfma_f32_16x16x32_bf16(af[mf], bf[nf], acc[mf][nf], 0, 0, 0);
    }

    #pragma unroll
    for (int mf = 0; mf < 4; ++mf)
        #pragma unroll
        for (int nf = 0; nf < 4; ++nf)
            #pragma unroll
            for (int r = 0; r < 4; ++r) {
                int m = m0 + wid * 64 + 16 * mf + (l >> 4) * 4 + r;
                int b = m >> 11, s = m & (S_ - 1);
                int e = 16 * nf + (l & 15);
                outw[((size_t)((b << 4) + h) * S_ + s) * E_ + e] = f2b(acc[mf][nf][r]);
            }
}

// ---------------- Flash attention (causal), bf16 MFMA, 2-phase pipelined ----------------
// grid: 768 1-D blocks = 256 CU x 3 resident, zero tail. Block n: g = n>>6 (0..11),
// bh = n&63 (XCD = n%8 = bh%8 -> per-XCD L2-resident K/V). Group g's q-tiles sum to
// exactly 44 KV-tile-units for every block -> perfect balance.
// Softmax: raw-score max, scale folded into fma+exp2, lane-partial row sums
// (reduced once in epilogue), defer-max rescale skip (THR=8 in log2 domain).
__global__ __launch_bounds__(256) void flash(const ushort* __restrict__ qg,
                                             const ushort* __restrict__ kg,
                                             const ushort* __restrict__ vtg,
                                             ushort* __restrict__ attn) {
    const int n = blockIdx.x;
    const int g = n >> 6;          // 0..11
    const int bh = n & 63;
    const int b = bh >> 4, h = bh & 15;
    const ushort* qb = qg + (size_t)bh * (S_ * E_);
    const ushort* kb = kg + (size_t)bh * (S_ * E_);
    const ushort* vb = vtg + (size_t)bh * (E_ * S_);

    __shared__ __align__(16) ushort Qs[64 * 64];      // [q][e]   swizzled
    __shared__ __align__(16) ushort Ks[2][64 * 64];   // [t][e]   swizzled, double-buffered
    __shared__ __align__(16) ushort Vs[2][64 * 64];   // [e][j]   swizzled, double-buffered
    __shared__ __align__(16) ushort Ps[4][16 * 64];   // per-wave [q16][j64] swizzled

    const int t = threadIdx.x, l = t & 63, wid = t >> 6;
    const float SC = 0.18033688f;                  // (1/sqrt(E)) * log2(e)
    const float NEG_INF = -__builtin_inff();
    const int ri_base = wid * 16 + ((l >> 4) << 2);
    const int cnt = GCNT[g];

    #pragma unroll 1
    for (int qi = 0; qi < cnt; ++qi) {
        const int qt = GQT[g][qi];

        // prologue: stage Q + first K/V tile
        #pragma unroll
        for (int it = 0; it < 2; ++it) {
            int i = it * 256 + t;
            int r = i >> 3, cs = i & 7, c = cs ^ (r & 7);
            GLD16(qb + (size_t)(qt * 64 + r) * E_ + c * 8, &Qs[i * 8]);
            GLD16(kb + (size_t)r * E_ + c * 8, &Ks[0][i * 8]);
            GLD16(vb + (size_t)r * S_ + c * 8, &Vs[0][i * 8]);
        }
        __syncthreads();

        short8 qf[2];
        #pragma unroll
        for (int ks = 0; ks < 2; ++ks) {
            int row = wid * 16 + (l & 15);
            int c = ((l >> 4) + 4 * ks) ^ (row & 7);
            qf[ks] = *(const short8*)&Qs[row * 64 + c * 8];
        }

        floatx4 o[4] = {};
        float mr[4], lr[4];
        #pragma unroll
        for (int r = 0; r < 4; ++r) { mr[r] = NEG_INF; lr[r] = 0.f; }

        int buf = 0;
        for (int jt = 0; jt <= qt; ++jt) {
            // issue next tile's staging BEFORE compute (latency hides under compute)
            if (jt < qt) {
                #pragma unroll
                for (int it = 0; it < 2; ++it) {
                    int i = it * 256 + t;
                    int r = i >> 3, cs = i & 7, c = cs ^ (r & 7);
                    GLD16(kb + (size_t)((jt + 1) * 64 + r) * E_ + c * 8, &Ks[buf ^ 1][i * 8]);
                    GLD16(vb + (size_t)r * S_ + (jt + 1) * 64 + c * 8, &Vs[buf ^ 1][i * 8]);
                }
            }

            // S = Q K^T on current buffer (raw scores)
            floatx4 s[4] = {};
            #pragma unroll
            for (int nf = 0; nf < 4; ++nf) {
                #pragma unroll
                for (int ks = 0; ks < 2; ++ks) {
                    int row = 16 * nf + (l & 15);
                    int c = ((l >> 4) + 4 * ks) ^ (row & 7);
                    short8 kf = *(const short8*)&Ks[buf][row * 64 + c * 8];
                    s[nf] = __builtin_amdgcn_mfma_f32_16x16x32_bf16(qf[ks], kf, s[nf], 0, 0, 0);
                }
            }

            // causal mask on diagonal tile only (raw scores, -inf)
            if (jt == qt) {
                #pragma unroll
                for (int nf = 0; nf < 4; ++nf) {
                    int cj = 16 * nf + (l & 15);
                    #pragma unroll
                    for (int r = 0; r < 4; ++r)
                        if (cj > ri_base + r) s[nf][r] = NEG_INF;
                }
            }

            // row max on raw scores + defer-max check
            float mxr[4]; bool ok = true;
            #pragma unroll
            for (int r = 0; r < 4; ++r) {
                float mx = fmaxf(fmaxf(s[0][r], s[1][r]), fmaxf(s[2][r], s[3][r]));
                mx = fmaxf(mx, __shfl_xor(mx, 1));
                mx = fmaxf(mx, __shfl_xor(mx, 2));
                mx = fmaxf(mx, __shfl_xor(mx, 4));
                mx = fmaxf(mx, __shfl_xor(mx, 8));
                mxr[r] = mx;
                ok = ok && ((mx - mr[r]) * SC <= 8.0f);
            }

            if (!__all(ok)) {   // rescale path (rare after warm-up)
                #pragma unroll
                for (int r = 0; r < 4; ++r) {
                    float mn = fmaxf(mr[r], mxr[r]);
                    float al = fast_exp2((mr[r] - mn) * SC);
                    mr[r] = mn;
                    lr[r] *= al;
                    #pragma unroll
                    for (int nf = 0; nf < 4; ++nf) o[nf][r] *= al;
                }
            }

            // exp2(fma) + lane-partial row sums (no shfl here)
            #pragma unroll
            for (int r = 0; r < 4; ++r) {
                float nm = -mr[r] * SC;
                float rs = 0.f;
                #pragma unroll
                for (int nf = 0; nf < 4; ++nf) {
                    float p = fast_exp2(fmaf(s[nf][r], SC, nm));
                    s[nf][r] = p;
                    rs += p;
                }
                lr[r] += rs;
            }

            // P -> wave-private LDS (packed bf16 cvt, swizzled u16 writes)
            #pragma unroll
            for (int nf = 0; nf < 4; ++nf) {
                int col = 16 * nf + (l & 15);
                int sw_hi = (col >> 3) << 3;   // swizzle chunk base, col&7 fixed
                #pragma unroll
                for (int rp = 0; rp < 2; ++rp) {
                    unsigned pk = cvt_pk_bf16(s[nf][2 * rp], s[nf][2 * rp + 1]);
                    int row0 = (l >> 4) * 4 + 2 * rp;
                    int a0 = row0 * 64 + ((sw_hi >> 3) ^ (row0 & 7)) * 8 + (col & 7);
                    int a1 = (row0 + 1) * 64 + ((sw_hi >> 3) ^ ((row0 + 1) & 7)) * 8 + (col & 7);
                    Ps[wid][a0] = (ushort)pk;
                    Ps[wid][a1] = (ushort)(pk >> 16);
                }
            }

            // O += P V
            short8 pf[2];
            #pragma unroll
            for (int ks = 0; ks < 2; ++ks) {
                int row = l & 15;
                int c = ((l >> 4) + 4 * ks) ^ (row & 7);
                pf[ks] = *(const short8*)&Ps[wid][row * 64 + c * 8];
            }
            #pragma unroll
            for (int nf = 0; nf < 4; ++nf) {
                #pragma unroll
                for (int ks = 0; ks < 2; ++ks) {
                    int row = 16 * nf + (l & 15);
                    int c = ((l >> 4) + 4 * ks) ^ (row & 7);
                    short8 vf = *(const short8*)&Vs[buf][row * 64 + c * 8];
                    o[nf] = __builtin_amdgcn_mfma_f32_16x16x32_bf16(pf[ks], vf, o[nf], 0, 0, 0);
                }
            }

            __syncthreads();   // drains this iteration's prefetch (vmcnt) + protects buf^1
            buf ^= 1;
        }

        // epilogue: reduce lane-partial sums, normalize, bounce via Ps for coalesced writes
        #pragma unroll
        for (int r = 0; r < 4; ++r) {
            float rs = lr[r];
            rs += __shfl_xor(rs, 1);
            rs += __shfl_xor(rs, 2);
            rs += __shfl_xor(rs, 4);
            rs += __shfl_xor(rs, 8);
            lr[r] = 1.0f / rs;
        }
        #pragma unroll
        for (int nf = 0; nf < 4; ++nf) {
            int col = 16 * nf + (l & 15);
            #pragma unroll
            for (int rp = 0; rp < 2; ++rp) {
                unsigned pk = cvt_pk_bf16(o[nf][2 * rp] * lr[2 * rp],
                                          o[nf][2 * rp + 1] * lr[2 * rp + 1]);
                int row0 = (l >> 4) * 4 + 2 * rp;
                int a0 = row0 * 64 + (((col >> 3)) ^ (row0 & 7)) * 8 + (col & 7);
                int a1 = (row0 + 1) * 64 + (((col >> 3)) ^ ((row0 + 1) & 7)) * 8 + (col & 7);
                Ps[wid][a0] = (ushort)pk;
                Ps[wid][a1] = (ushort)(pk >> 16);
            }
        }
        #pragma unroll
        for (int it = 0; it < 2; ++it) {               // 16 rows x 8 chunks per wave
            int i = it * 64 + l;
            int row = i >> 3, cc = i & 7;
            int c = cc ^ (row & 7);
            short8 vv = *(const short8*)&Ps[wid][row * 64 + c * 8];
            int s_abs = qt * 64 + wid * 16 + row;
            *(short8*)&attn[((size_t)(b * S_ + s_abs)) * D_ + h * E_ + cc * 8] = vv;
        }
        __syncthreads();   // Ps/Qs reuse boundary before next q-tile's staging
    }
}

// ---------------- output projection: [8192x1024] x Wp^T + bp, bf16 MFMA, fp32 out ----------------
__global__ __launch_bounds__(256) void out_proj(const ushort* __restrict__ a,
                                                const ushort* __restrict__ wpb,
                                                const float* __restrict__ bp,
                                                float* __restrict__ out) {
    const int m0 = blockIdx.x * 128;
    const int n0 = blockIdx.y * 128;

    __shared__ __align__(16) ushort As[128 * 32];
    __shared__ __align__(16) ushort Bs[128 * 32];

    const int t = threadIdx.x, l = t & 63, wid = t >> 6;
    const int wm = (wid & 1) * 64, wn = (wid >> 1) * 64;
    floatx4 acc[4][4] = {};

    for (int k0 = 0; k0 < D_; k0 += 32) {
        __syncthreads();
        #pragma unroll
        for (int it = 0; it < 2; ++it) {
            int i = it * 256 + t;
            int r = i >> 2, cs = i & 3;
            int c = cs ^ ((r >> 1) & 3);
            GLD16(a + (size_t)(m0 + r) * D_ + k0 + c * 8, &As[i * 8]);
            GLD16(wpb + (size_t)(n0 + r) * D_ + k0 + c * 8, &Bs[i * 8]);
        }
        __syncthreads();

        short8 af[4], bf[4];
        #pragma unroll
        for (int mf = 0; mf < 4; ++mf) {
            int row = wm + 16 * mf + (l & 15);
            int c = (l >> 4) ^ ((row >> 1) & 3);
            af[mf] = *(const short8*)&As[row * 32 + c * 8];
        }
        #pragma unroll
        for (int nf = 0; nf < 4; ++nf) {
            int row = wn + 16 * nf + (l & 15);
            int c = (l >> 4) ^ ((row >> 1) & 3);
            bf[nf] = *(const short8*)&Bs[row * 32 + c * 8];
        }
        #pragma unroll
        for (int mf = 0; mf < 4; ++mf)
            #pragma unroll
            for (int nf = 0; nf < 4; ++nf)
                acc[mf][nf] = __builtin_amdgcn_mfma_f32_16x16x32_bf16(af[mf], bf[nf], acc[mf][nf], 0, 0, 0);
    }

    #pragma unroll
    for (int nf = 0; nf < 4; ++nf) {
        int col = n0 + wn + 16 * nf + (l & 15);
        float bias = bp[col];
        #pragma unroll
        for (int mf = 0; mf < 4; ++mf)
            #pragma unroll
            for (int r = 0; r < 4; ++r) {
                int m = m0 + wm + 16 * mf + (l >> 4) * 4 + r;
                out[(size_t)m * D_ + col] = acc[mf][nf][r] + bias;
            }
    }
}

extern "C" void kernel_launch(void* const* d_in, const int* in_sizes, int n_in,
                              void* d_out, int out_size, void* d_ws, size_t ws_size,
                              hipStream_t stream) {
    const float* x  = (const float*)d_in[0];
    const float* Wq = (const float*)d_in[1];
    const float* Wk = (const float*)d_in[2];
    const float* Wv = (const float*)d_in[3];
    const float* Wp = (const float*)d_in[4];
    const float* bp = (const float*)d_in[5];

    ushort* ws = (ushort*)d_ws;
    const size_t NX  = (size_t)M_ * D_;          // 8M
    const size_t NW  = (size_t)48 * E_ * D_;     // 3.15M
    const size_t NP  = (size_t)D_ * D_;          // 1M
    const size_t QSZ = (size_t)B_ * H_ * S_ * E_;// 8M
    ushort* xb    = ws;
    ushort* wt    = xb + NX;
    ushort* wpb   = wt + NW;
    ushort* qkvb  = wpb + NP;        // q | k | v
    ushort* vt    = qkvb + 3 * QSZ;
    ushort* attnb = vt + QSZ;        // total ~104 MB

    cast_bf16  <<<2048, 256, 0, stream>>>(x, xb, (int)(NX / 8));
    cast_bf16  <<<512, 256, 0, stream>>>(Wp, wpb, (int)(NP / 8));
    transpose_w<<<dim3(16, 48), 256, 0, stream>>>(Wq, Wk, Wv, wt);
    gemm_qkv   <<<dim3(M_ / 256, 48), 256, 0, stream>>>(xb, wt, qkvb);
    transpose_v<<<dim3(S_ / 64, B_ * H_), 256, 0, stream>>>(qkvb + 2 * QSZ, vt);
    flash      <<<768, 256, 0, stream>>>(qkvb, qkvb + QSZ, vt, attnb);
    out_proj   <<<dim3(M_ / 128, D_ / 128), 256, 0, stream>>>(attnb, wpb, bp, (float*)d_out);
}